// Round 1
// baseline (11344.513 us; speedup 1.0000x reference)
//
#include <hip/hip_runtime.h>
#include <math.h>

#define DEV __device__ __forceinline__

DEV float wredf(float v){
  v += __shfl_xor(v, 32, 64);
  v += __shfl_xor(v, 16, 64);
  v += __shfl_xor(v, 8, 64);
  v += __shfl_xor(v, 4, 64);
  v += __shfl_xor(v, 2, 64);
  v += __shfl_xor(v, 1, 64);
  return v;
}

// ---------------- h0: (B,3,256,256) -> (B,256,256,4) with time ----------------
__global__ void h0_kernel(const float* __restrict__ x, float* __restrict__ h0){
  int idx = blockIdx.x*256 + threadIdx.x;            // < 32*65536
  int b = idx >> 16, p = idx & 65535;
  const float* xb = x + (size_t)b*3*65536;
  float v0 = xb[p], v1 = xb[65536 + p], v2 = xb[131072 + p];
  float4 o;
  o.x = sqrtf(v0*v0 + v1*v1 + v2*v2 + 1.f);
  o.y = v0; o.z = v1; o.w = v2;
  *(float4*)&h0[(size_t)idx*4] = o;
}

// ---------------- conv GEMM: 64 pixels x 64 out-channels, K chunks of 32 -----
__global__ __launch_bounds__(256) void conv_kernel(
    const float* __restrict__ hin, const float* __restrict__ Wm,
    const float* __restrict__ bias, float* __restrict__ yout,
    int Hin, int Win, int Cin, int Ho, int Wo, int Cout, int K){
  __shared__ __align__(16) float A[32][64];
  __shared__ __align__(16) float Wb[32][64];
  int tid = threadIdx.x;
  int tilesX = Wo >> 3;
  int tile = blockIdx.x;
  int b = blockIdx.y;
  int zbase = blockIdx.z * 64;
  int oy0 = (tile / tilesX) * 8, ox0 = (tile % tilesX) * 8;
  int tx = tid & 15, ty = tid >> 4;
  float acc[4][4] = {};
  int nchunks = (K + 31) / 32;
  for (int ch = 0; ch < nchunks; ++ch){
    int k0 = ch * 32;
    // stage patch tile A[kk][m]
    for (int idx = tid; idx < 2048; idx += 256){
      int kk = idx >> 6, m = idx & 63;
      int k = k0 + kk;
      float v = 0.f;
      if (k > 0 && k < K){
        int t = k - 1; int c = t / 9; int kp = t - c*9;
        int py = oy0 + (m >> 3), px = ox0 + (m & 7);
        int iy = py*2 + kp/3 - 1;
        int ix = px*2 + (kp - (kp/3)*3) - 1;
        if ((unsigned)iy < (unsigned)Hin && (unsigned)ix < (unsigned)Win)
          v = hin[(((size_t)b*Hin + iy)*Win + ix)*Cin + 1 + c];
      }
      A[kk][m] = v;
    }
    if (k0 == 0 && tid < 64){
      int m = tid;
      int py = oy0 + (m >> 3), px = ox0 + (m & 7);
      float s = 0.f;
      for (int kp = 0; kp < 9; ++kp){
        int iy = py*2 + kp/3 - 1, ix = px*2 + kp%3 - 1;
        float tv = 1.f;  // zero-padded point clamps to sqrt(K)=1
        if ((unsigned)iy < (unsigned)Hin && (unsigned)ix < (unsigned)Win)
          tv = fmaxf(hin[(((size_t)b*Hin + iy)*Win + ix)*Cin], 1.f);
        s += tv*tv;
      }
      A[0][m] = sqrtf(fmaxf(s - 8.f, 0.f));
    }
    // stage W chunk (rows 1..Cout-1; row 0 of W is dropped by the reference)
    for (int idx = tid; idx < 2048; idx += 256){
      int kk = idx >> 6, n = idx & 63;
      int k = k0 + kk;
      int o = zbase + n + 1;
      Wb[kk][n] = (k < K && o < Cout) ? Wm[(size_t)o*K + k] : 0.f;
    }
    __syncthreads();
    #pragma unroll
    for (int kk = 0; kk < 32; ++kk){
      float4 a4 = *(const float4*)&A[kk][tx*4];
      float4 w4 = *(const float4*)&Wb[kk][ty*4];
      float av[4] = {a4.x, a4.y, a4.z, a4.w};
      float wv[4] = {w4.x, w4.y, w4.z, w4.w};
      #pragma unroll
      for (int i = 0; i < 4; ++i)
        #pragma unroll
        for (int j = 0; j < 4; ++j)
          acc[i][j] = fmaf(av[i], wv[j], acc[i][j]);
    }
    __syncthreads();
  }
  #pragma unroll
  for (int j = 0; j < 4; ++j){
    int o = zbase + ty*4 + j + 1;
    if (o < Cout){
      float bv = bias[o];
      #pragma unroll
      for (int i = 0; i < 4; ++i){
        int m = tx*4 + i;
        int py = oy0 + (m >> 3), px = ox0 + (m & 7);
        yout[(((size_t)b*Ho + py)*Wo + px)*Cout + o] = acc[i][j] + bv;
      }
    }
  }
}

// ---------------- fill time channel: y[...,0] = sqrt(sum space^2 + 1) -------
__global__ void time_kernel(float* __restrict__ y, int P, int C){
  int wv = threadIdx.x >> 6, lane = threadIdx.x & 63;
  int p = blockIdx.x*4 + wv;
  if (p >= P) return;
  float* yp = y + (size_t)p * C;
  float s = 0.f;
  for (int c = 1 + lane; c < C; c += 64){ float v = yp[c]; s += v*v; }
  s = wredf(s);
  if (lane == 0) yp[0] = sqrtf(s + 1.f);
}

// ---------------- per-(b,c) channel sums over N -----------------------------
__global__ void rsum_kernel(const float* __restrict__ y, float* __restrict__ red,
                            int N, int C, int SPLIT){
  int b = blockIdx.y;
  int nper = (N + SPLIT - 1) / SPLIT;
  int n0 = blockIdx.x * nper, n1 = min(n0 + nper, N);
  int tid = threadIdx.x;
  float a0 = 0.f, a1 = 0.f;
  for (int n = n0; n < n1; ++n){
    const float* yp = y + ((size_t)b*N + n) * C;
    if (tid < C) a0 += yp[tid];
    if (tid + 256 < C) a1 += yp[tid + 256];
  }
  if (tid < C) atomicAdd(&red[b*C + tid], a0);
  if (tid + 256 < C) atomicAdd(&red[b*C + tid + 256], a1);
}

// ---------------- double centroid -> mean vector; zero scratch scalars ------
__global__ void bn_stats_kernel(const float* __restrict__ red, float* __restrict__ mean,
                                float* __restrict__ scal, int B, int N, int C){
  __shared__ float s[256];
  int tid = threadIdx.x;
  float acc2a = 0.f, acc2b = 0.f;
  for (int b = 0; b < B; ++b){
    float va = (tid < C) ? red[b*C + tid] / (float)N : 0.f;
    float vb = (tid + 256 < C) ? red[b*C + tid + 256] / (float)N : 0.f;
    float pr = ((tid == 0) ? -va*va : va*va) + vb*vb;   // Minkowski <avg,avg>
    s[tid] = pr; __syncthreads();
    for (int st = 128; st; st >>= 1){ if (tid < st) s[tid] += s[tid+st]; __syncthreads(); }
    float lo = s[0]; __syncthreads();
    float den = sqrtf(fmaxf(fabsf(lo), 1e-8f));
    acc2a += va / den; acc2b += vb / den;
  }
  acc2a /= (float)B; acc2b /= (float)B;
  float pr = ((tid == 0) ? -acc2a*acc2a : acc2a*acc2a) + acc2b*acc2b;
  s[tid] = pr; __syncthreads();
  for (int st = 128; st; st >>= 1){ if (tid < st) s[tid] += s[tid+st]; __syncthreads(); }
  float den2 = sqrtf(fmaxf(fabsf(s[0]), 1e-8f));
  if (tid < C) mean[tid] = acc2a / den2;
  if (tid + 256 < C) mean[tid + 256] = acc2b / den2;
  if (tid < 40) scal[tid] = 0.f;   // var accumulator + flatten square-sums
}

// ---------------- tangent-norm (Frechet variance) accumulation --------------
__global__ void bn_var_kernel(const float* __restrict__ y, const float* __restrict__ mean,
                              float* __restrict__ scal, int P, int C){
  __shared__ float smean[260];
  for (int i = threadIdx.x; i < C; i += blockDim.x) smean[i] = mean[i];
  __syncthreads();
  int wv = threadIdx.x >> 6, lane = threadIdx.x & 63;
  int p = blockIdx.x*4 + wv;
  if (p >= P) return;
  const float* yp = y + (size_t)p * C;
  float yv[5], ms[5], nom[5];
  #pragma unroll
  for (int j = 0; j < 5; ++j){
    int c = lane + 64*j;
    yv[j] = (c < C) ? yp[c] : 0.f;
    ms[j] = (c < C) ? smean[c] : 0.f;
  }
  float m0 = smean[0];
  float d1 = 0.f;
  #pragma unroll
  for (int j = 0; j < 5; ++j){
    int c = lane + 64*j;
    float prd = yv[j]*ms[j];
    d1 += (c == 0) ? -prd : prd;
  }
  float xy = wredf(d1);
  float z = fmaxf(-xy, 1.f + 1e-7f);
  float dist = acoshf(z);
  float d2 = 0.f;
  #pragma unroll
  for (int j = 0; j < 5; ++j){
    int c = lane + 64*j;
    nom[j] = yv[j] + xy*ms[j];
    float prd = nom[j]*nom[j];
    d2 += (c == 0) ? -prd : prd;
  }
  float den = sqrtf(fmaxf(wredf(d2), 1e-8f));
  float sc = dist / den;
  float u0 = __shfl(nom[0], 0, 64) * sc;
  float corr = -u0 / (1.f + m0);
  float nsum = 0.f;
  #pragma unroll
  for (int j = 0; j < 5; ++j){
    int c = lane + 64*j;
    float uc = nom[j]*sc + corr*(ms[j] + ((c == 0) ? 1.f : 0.f));
    nsum += uc*uc;
  }
  nsum = wredf(nsum);
  if (lane == 0) atomicAdd(scal, sqrtf(nsum));
}

// ---------------- BN apply: rescale, transport to beta, expmap, relu, time --
__global__ void bn_apply_kernel(const float* __restrict__ y, const float* __restrict__ mean,
                                const float* __restrict__ beta, const float* __restrict__ gamma,
                                const float* __restrict__ scal, float* __restrict__ hout,
                                int P, int C){
  __shared__ float smean[260];
  __shared__ float sbeta[260];
  for (int i = threadIdx.x; i < C; i += blockDim.x){ smean[i] = mean[i]; sbeta[i] = beta[i]; }
  __syncthreads();
  int wv = threadIdx.x >> 6, lane = threadIdx.x & 63;
  int p = blockIdx.x*4 + wv;
  if (p >= P) return;
  const float* yp = y + (size_t)p * C;
  float yv[5], ms[5], bs[5], nom[5], uc[5], u2[5];
  #pragma unroll
  for (int j = 0; j < 5; ++j){
    int c = lane + 64*j;
    yv[j] = (c < C) ? yp[c] : 0.f;
    ms[j] = (c < C) ? smean[c] : 0.f;
    bs[j] = (c < C) ? sbeta[c] : 0.f;
  }
  float m0 = smean[0], b0 = sbeta[0];
  float d1 = 0.f;
  #pragma unroll
  for (int j = 0; j < 5; ++j){
    int c = lane + 64*j;
    float prd = yv[j]*ms[j];
    d1 += (c == 0) ? -prd : prd;
  }
  float xy = wredf(d1);
  float z = fmaxf(-xy, 1.f + 1e-7f);
  float dist = acoshf(z);
  float d2 = 0.f;
  #pragma unroll
  for (int j = 0; j < 5; ++j){
    nom[j] = yv[j] + xy*ms[j];
    int c = lane + 64*j;
    float prd = nom[j]*nom[j];
    d2 += (c == 0) ? -prd : prd;
  }
  float den = sqrtf(fmaxf(wredf(d2), 1e-8f));
  float sc = dist / den;
  float u0 = __shfl(nom[0], 0, 64) * sc;
  float corr = -u0 / (1.f + m0);
  float var = scal[0] / (float)P;
  float g = gamma[0] / (var + 1e-5f);
  #pragma unroll
  for (int j = 0; j < 5; ++j){
    int c = lane + 64*j;
    uc[j] = (nom[j]*sc + corr*(ms[j] + ((c == 0) ? 1.f : 0.f))) * g;
  }
  float d3 = 0.f;
  #pragma unroll
  for (int j = 0; j < 5; ++j){
    int c = lane + 64*j;
    float prd = uc[j]*bs[j];
    d3 += (c == 0) ? -prd : prd;
  }
  float cb = wredf(d3) / (1.f + b0);
  float d4 = 0.f;
  #pragma unroll
  for (int j = 0; j < 5; ++j){
    int c = lane + 64*j;
    u2[j] = uc[j] + cb*(bs[j] + ((c == 0) ? 1.f : 0.f));
    float prd = u2[j]*u2[j];
    d4 += (c == 0) ? -prd : prd;
  }
  float nu = sqrtf(fmaxf(wredf(d4), 1e-8f));
  float ch = coshf(nu), shn = sinhf(nu) / nu;
  float ssum = 0.f;
  float* hp = hout + (size_t)p * C;
  #pragma unroll
  for (int j = 0; j < 5; ++j){
    int c = lane + 64*j;
    if (c > 0 && c < C){
      float r = ch*sbeta[c] + shn*u2[j];
      r = fmaxf(r, 0.f);
      hp[c] = r;
      ssum += r*r;
    }
  }
  ssum = wredf(ssum);
  if (lane == 0) hp[0] = sqrtf(ssum + 1.f);
}

// ---------------- flatten h4 (B,256,257) -> (B,65537) + square sums ---------
__global__ void flatten_kernel(const float* __restrict__ h, float* __restrict__ flat,
                               float* __restrict__ scal){
  __shared__ float s[256];
  int tid = threadIdx.x;
  int idx = blockIdx.x*256 + tid;
  int b = idx >> 16, r = idx & 65535;
  int n = r >> 8, c = r & 255;
  float v = h[(((size_t)b << 8) + n)*257 + 1 + c];
  flat[(size_t)b*65537 + 1 + r] = v;
  s[tid] = v*v; __syncthreads();
  for (int st = 128; st; st >>= 1){ if (tid < st) s[tid] += s[tid+st]; __syncthreads(); }
  if (tid == 0) atomicAdd(&scal[1 + b], s[0]);
}

__global__ void flat_time_kernel(float* __restrict__ flat, const float* __restrict__ scal){
  int b = threadIdx.x;
  if (b < 32) flat[(size_t)b*65537] = sqrtf(scal[1 + b] + 1.f);
}

// ---------------- head GEMM: split-K, h in LDS, W streamed ------------------
__global__ __launch_bounds__(256) void fgemm_kernel(const float* __restrict__ flat,
    const float* __restrict__ wm, const float* __restrict__ wv,
    float* __restrict__ mvacc){
  __shared__ float hch[256*33];
  int tid = threadIdx.x;
  int k0 = blockIdx.x * 256;
  int obase = blockIdx.y * 32;
  {
    int k = k0 + tid;
    for (int b2 = 0; b2 < 32; ++b2){
      float v = (k < 65537) ? flat[(size_t)b2*65537 + k] : 0.f;
      hch[tid*33 + b2] = v;
    }
  }
  __syncthreads();
  int b = tid & 31, os = tid >> 5;
  const float* rows[4];
  float accv[4] = {0.f, 0.f, 0.f, 0.f};
  #pragma unroll
  for (int r = 0; r < 4; ++r){
    int o = obase + os + r*8;
    rows[r] = (o < 512) ? (wm + (size_t)(o + 1)*65537) : (wv + (size_t)(o - 511)*65537);
  }
  int kRem = min(256, 65537 - k0);
  int k4 = kRem & ~3;
  for (int k = 0; k < k4; k += 4){
    float h0 = hch[(k+0)*33 + b], h1 = hch[(k+1)*33 + b];
    float h2 = hch[(k+2)*33 + b], h3 = hch[(k+3)*33 + b];
    #pragma unroll
    for (int r = 0; r < 4; ++r){
      const float* rw = rows[r] + k0 + k;
      accv[r] += h0*rw[0] + h1*rw[1] + h2*rw[2] + h3*rw[3];
    }
  }
  for (int k = k4; k < kRem; ++k){
    float hv = hch[k*33 + b];
    #pragma unroll
    for (int r = 0; r < 4; ++r) accv[r] += hv * rows[r][k0 + k];
  }
  #pragma unroll
  for (int r = 0; r < 4; ++r){
    int o = obase + os + r*8;
    atomicAdd(&mvacc[o*32 + b], accv[r]);
  }
}

// ---------------- finalize: bias, time, softplus ----------------------------
__global__ void finalize_kernel(const float* __restrict__ mvacc, const float* __restrict__ bm,
                                const float* __restrict__ bv, float* __restrict__ out){
  __shared__ float s[256];
  int b = blockIdx.x, tid = threadIdx.x;
  float m0 = mvacc[tid*32 + b] + bm[tid + 1];
  float m1 = mvacc[(tid + 256)*32 + b] + bm[tid + 257];
  s[tid] = m0*m0 + m1*m1; __syncthreads();
  for (int st = 128; st; st >>= 1){ if (tid < st) s[tid] += s[tid+st]; __syncthreads(); }
  float t = sqrtf(s[0] + 1.f);
  float* om = out + (size_t)b*513;
  om[1 + tid] = m0;
  om[1 + tid + 256] = m1;
  if (tid == 0) om[0] = t;
  float v0 = mvacc[(512 + tid)*32 + b] + bv[tid + 1];
  float v1 = mvacc[(512 + tid + 256)*32 + b] + bv[tid + 257];
  float sp0 = fmaxf(v0, 0.f) + log1pf(expf(-fabsf(v0)));
  float sp1 = fmaxf(v1, 0.f) + log1pf(expf(-fabsf(v1)));
  float* ov = out + 32*513 + (size_t)b*512;
  ov[tid] = fmaxf(sp0, 1e-5f);
  ov[tid + 256] = fmaxf(sp1, 1e-5f);
}

extern "C" void kernel_launch(void* const* d_in, const int* in_sizes, int n_in,
                              void* d_out, int out_size, void* d_ws, size_t ws_size,
                              hipStream_t stream){
  const float* x  = (const float*)d_in[0];
  const float* cw[4] = {(const float*)d_in[1], (const float*)d_in[5], (const float*)d_in[9],  (const float*)d_in[13]};
  const float* cb[4] = {(const float*)d_in[2], (const float*)d_in[6], (const float*)d_in[10], (const float*)d_in[14]};
  const float* bb[4] = {(const float*)d_in[3], (const float*)d_in[7], (const float*)d_in[11], (const float*)d_in[15]};
  const float* bg[4] = {(const float*)d_in[4], (const float*)d_in[8], (const float*)d_in[12], (const float*)d_in[16]};
  const float* wm = (const float*)d_in[17];
  const float* bm = (const float*)d_in[18];
  const float* wv = (const float*)d_in[19];
  const float* bv = (const float*)d_in[20];
  float* ws = (float*)d_ws;

  // workspace layout (floats)
  float* S[3] = { ws, ws + 9000000, ws + 26400000 };      // 9M / 17.4M / 17.4M
  float* red1  = ws + 43800000;                           // up to 32*257
  float* meanp = ws + 43810000;                           // up to 257
  float* scal  = ws + 43811000;                           // [0]=var sum, [1..32]=flat sq
  float* mvacc = ws + 43812000;                           // 1024*32

  hipMemsetAsync(mvacc, 0, 32768*sizeof(float), stream);

  h0_kernel<<<8192, 256, 0, stream>>>(x, S[0]);

  const int HinA[4]  = {256, 128, 64, 32};
  const int SinA[4]  = {3, 32, 64, 128};
  const int HoA[4]   = {128, 64, 32, 16};
  const int CoutA[4] = {33, 65, 129, 257};
  const int KA[4]    = {28, 289, 577, 1153};

  int cur = 0;
  for (int i = 0; i < 4; ++i){
    int Hin = HinA[i], Win = HinA[i], Cin = SinA[i] + 1;
    int Ho = HoA[i], Wo = HoA[i], Cout = CoutA[i], K = KA[i];
    float* hin  = S[cur];
    float* y    = S[(cur + 1) % 3];
    float* hout = S[(cur + 2) % 3];
    int tiles = (Ho/8) * (Wo/8);
    dim3 g(tiles, 32, (Cout - 1 + 63)/64);
    conv_kernel<<<g, 256, 0, stream>>>(hin, cw[i], cb[i], y, Hin, Win, Cin, Ho, Wo, Cout, K);
    int N = Ho * Wo;
    int P = 32 * N;
    time_kernel<<<(P + 3)/4, 256, 0, stream>>>(y, P, Cout);
    hipMemsetAsync(red1, 0, 32*Cout*sizeof(float), stream);
    int SPLIT = (N >= 16384) ? 64 : ((N >= 4096) ? 16 : ((N >= 1024) ? 4 : 1));
    rsum_kernel<<<dim3(SPLIT, 32), 256, 0, stream>>>(y, red1, N, Cout, SPLIT);
    bn_stats_kernel<<<1, 256, 0, stream>>>(red1, meanp, scal, 32, N, Cout);
    bn_var_kernel<<<(P + 3)/4, 256, 0, stream>>>(y, meanp, scal, P, Cout);
    bn_apply_kernel<<<(P + 3)/4, 256, 0, stream>>>(y, meanp, bb[i], bg[i], scal, hout, P, Cout);
    cur = (cur + 2) % 3;
  }

  // h4 now in S[cur] (== S[2]); flatten into S[0]
  float* flatp = S[0];
  flatten_kernel<<<8192, 256, 0, stream>>>(S[cur], flatp, scal);
  flat_time_kernel<<<1, 64, 0, stream>>>(flatp, scal);
  fgemm_kernel<<<dim3(257, 32), 256, 0, stream>>>(flatp, wm, wv, mvacc);
  finalize_kernel<<<32, 256, 0, stream>>>(mvacc, bm, bv, (float*)d_out);
}

// Round 2
// 2760.518 us; speedup vs baseline: 4.1096x; 4.1096x over previous
//
#include <hip/hip_runtime.h>
#include <math.h>

#define DEV __device__ __forceinline__

DEV float wredf(float v){
  v += __shfl_xor(v, 32, 64);
  v += __shfl_xor(v, 16, 64);
  v += __shfl_xor(v, 8, 64);
  v += __shfl_xor(v, 4, 64);
  v += __shfl_xor(v, 2, 64);
  v += __shfl_xor(v, 1, 64);
  return v;
}

// ---------------- h0: (B,3,256,256) -> (B,256,256,4) with time ----------------
__global__ void h0_kernel(const float* __restrict__ x, float* __restrict__ h0){
  int idx = blockIdx.x*256 + threadIdx.x;            // < 32*65536
  int b = idx >> 16, p = idx & 65535;
  const float* xb = x + (size_t)b*3*65536;
  float v0 = xb[p], v1 = xb[65536 + p], v2 = xb[131072 + p];
  float4 o;
  o.x = sqrtf(v0*v0 + v1*v1 + v2*v2 + 1.f);
  o.y = v0; o.z = v1; o.w = v2;
  *(float4*)&h0[(size_t)idx*4] = o;
}

// ---------------- conv GEMM: 64 pixels x 64 out-channels, K chunks of 32 -----
__global__ __launch_bounds__(256) void conv_kernel(
    const float* __restrict__ hin, const float* __restrict__ Wm,
    const float* __restrict__ bias, float* __restrict__ yout,
    int Hin, int Win, int Cin, int Ho, int Wo, int Cout, int K){
  __shared__ __align__(16) float A[32][64];
  __shared__ __align__(16) float Wb[32][64];
  int tid = threadIdx.x;
  int tilesX = Wo >> 3;
  int tile = blockIdx.x;
  int b = blockIdx.y;
  int zbase = blockIdx.z * 64;
  int oy0 = (tile / tilesX) * 8, ox0 = (tile % tilesX) * 8;
  int tx = tid & 15, ty = tid >> 4;
  float acc[4][4] = {};
  int nchunks = (K + 31) / 32;
  for (int ch = 0; ch < nchunks; ++ch){
    int k0 = ch * 32;
    // stage patch tile A[kk][m]
    for (int idx = tid; idx < 2048; idx += 256){
      int kk = idx >> 6, m = idx & 63;
      int k = k0 + kk;
      float v = 0.f;
      if (k > 0 && k < K){
        int t = k - 1; int c = t / 9; int kp = t - c*9;
        int py = oy0 + (m >> 3), px = ox0 + (m & 7);
        int iy = py*2 + kp/3 - 1;
        int ix = px*2 + (kp - (kp/3)*3) - 1;
        if ((unsigned)iy < (unsigned)Hin && (unsigned)ix < (unsigned)Win)
          v = hin[(((size_t)b*Hin + iy)*Win + ix)*Cin + 1 + c];
      }
      A[kk][m] = v;
    }
    if (k0 == 0 && tid < 64){
      int m = tid;
      int py = oy0 + (m >> 3), px = ox0 + (m & 7);
      float s = 0.f;
      for (int kp = 0; kp < 9; ++kp){
        int iy = py*2 + kp/3 - 1, ix = px*2 + kp%3 - 1;
        float tv = 1.f;  // zero-padded point clamps to sqrt(K)=1
        if ((unsigned)iy < (unsigned)Hin && (unsigned)ix < (unsigned)Win)
          tv = fmaxf(hin[(((size_t)b*Hin + iy)*Win + ix)*Cin], 1.f);
        s += tv*tv;
      }
      A[0][m] = sqrtf(fmaxf(s - 8.f, 0.f));
    }
    // stage W chunk (rows 1..Cout-1; row 0 of W is dropped by the reference)
    for (int idx = tid; idx < 2048; idx += 256){
      int kk = idx >> 6, n = idx & 63;
      int k = k0 + kk;
      int o = zbase + n + 1;
      Wb[kk][n] = (k < K && o < Cout) ? Wm[(size_t)o*K + k] : 0.f;
    }
    __syncthreads();
    #pragma unroll
    for (int kk = 0; kk < 32; ++kk){
      float4 a4 = *(const float4*)&A[kk][tx*4];
      float4 w4 = *(const float4*)&Wb[kk][ty*4];
      float av[4] = {a4.x, a4.y, a4.z, a4.w};
      float wv[4] = {w4.x, w4.y, w4.z, w4.w};
      #pragma unroll
      for (int i = 0; i < 4; ++i)
        #pragma unroll
        for (int j = 0; j < 4; ++j)
          acc[i][j] = fmaf(av[i], wv[j], acc[i][j]);
    }
    __syncthreads();
  }
  #pragma unroll
  for (int j = 0; j < 4; ++j){
    int o = zbase + ty*4 + j + 1;
    if (o < Cout){
      float bv = bias[o];
      #pragma unroll
      for (int i = 0; i < 4; ++i){
        int m = tx*4 + i;
        int py = oy0 + (m >> 3), px = ox0 + (m & 7);
        yout[(((size_t)b*Ho + py)*Wo + px)*Cout + o] = acc[i][j] + bv;
      }
    }
  }
}

// ---------------- fill time channel: y[...,0] = sqrt(sum space^2 + 1) -------
__global__ void time_kernel(float* __restrict__ y, int P, int C){
  int wv = threadIdx.x >> 6, lane = threadIdx.x & 63;
  int p = blockIdx.x*4 + wv;
  if (p >= P) return;
  float* yp = y + (size_t)p * C;
  float s = 0.f;
  for (int c = 1 + lane; c < C; c += 64){ float v = yp[c]; s += v*v; }
  s = wredf(s);
  if (lane == 0) yp[0] = sqrtf(s + 1.f);
}

// ---------------- per-(b,c) channel sums over N -----------------------------
__global__ void rsum_kernel(const float* __restrict__ y, float* __restrict__ red,
                            int N, int C, int SPLIT){
  int b = blockIdx.y;
  int nper = (N + SPLIT - 1) / SPLIT;
  int n0 = blockIdx.x * nper, n1 = min(n0 + nper, N);
  int tid = threadIdx.x;
  float a0 = 0.f, a1 = 0.f;
  for (int n = n0; n < n1; ++n){
    const float* yp = y + ((size_t)b*N + n) * C;
    if (tid < C) a0 += yp[tid];
    if (tid + 256 < C) a1 += yp[tid + 256];
  }
  if (tid < C) atomicAdd(&red[b*C + tid], a0);
  if (tid + 256 < C) atomicAdd(&red[b*C + tid + 256], a1);
}

// ---------------- double centroid -> mean vector; zero scratch scalars ------
__global__ void bn_stats_kernel(const float* __restrict__ red, float* __restrict__ mean,
                                float* __restrict__ scal, int B, int N, int C){
  __shared__ float s[256];
  int tid = threadIdx.x;
  float acc2a = 0.f, acc2b = 0.f;
  for (int b = 0; b < B; ++b){
    float va = (tid < C) ? red[b*C + tid] / (float)N : 0.f;
    float vb = (tid + 256 < C) ? red[b*C + tid + 256] / (float)N : 0.f;
    float pr = ((tid == 0) ? -va*va : va*va) + vb*vb;   // Minkowski <avg,avg>
    s[tid] = pr; __syncthreads();
    for (int st = 128; st; st >>= 1){ if (tid < st) s[tid] += s[tid+st]; __syncthreads(); }
    float lo = s[0]; __syncthreads();
    float den = sqrtf(fmaxf(fabsf(lo), 1e-8f));
    acc2a += va / den; acc2b += vb / den;
  }
  acc2a /= (float)B; acc2b /= (float)B;
  float pr = ((tid == 0) ? -acc2a*acc2a : acc2a*acc2a) + acc2b*acc2b;
  s[tid] = pr; __syncthreads();
  for (int st = 128; st; st >>= 1){ if (tid < st) s[tid] += s[tid+st]; __syncthreads(); }
  float den2 = sqrtf(fmaxf(fabsf(s[0]), 1e-8f));
  if (tid < C) mean[tid] = acc2a / den2;
  if (tid + 256 < C) mean[tid + 256] = acc2b / den2;
  if (tid < 40) scal[tid] = 0.f;   // var accumulator + flatten square-sums
}

// ---------------- tangent-norm (Frechet variance) accumulation --------------
// Grid-stride; one atomicAdd per BLOCK (was: one per point -> 524k serialized
// atomics on one address = 6.6 ms. Atomic count now == gridDim.x = 2048).
__global__ void bn_var_kernel(const float* __restrict__ y, const float* __restrict__ mean,
                              float* __restrict__ scal, int P, int C){
  __shared__ float smean[260];
  __shared__ float part[4];
  for (int i = threadIdx.x; i < C; i += blockDim.x) smean[i] = mean[i];
  __syncthreads();
  int wv = threadIdx.x >> 6, lane = threadIdx.x & 63;
  int nwaves = gridDim.x * 4;
  float m0 = smean[0];
  float ms[5];
  #pragma unroll
  for (int j = 0; j < 5; ++j){
    int c = lane + 64*j;
    ms[j] = (c < C) ? smean[c] : 0.f;
  }
  float vsum = 0.f;
  for (int p = blockIdx.x*4 + wv; p < P; p += nwaves){
    const float* yp = y + (size_t)p * C;
    float yv[5], nom[5];
    #pragma unroll
    for (int j = 0; j < 5; ++j){
      int c = lane + 64*j;
      yv[j] = (c < C) ? yp[c] : 0.f;
    }
    float d1 = 0.f;
    #pragma unroll
    for (int j = 0; j < 5; ++j){
      int c = lane + 64*j;
      float prd = yv[j]*ms[j];
      d1 += (c == 0) ? -prd : prd;
    }
    float xy = wredf(d1);
    float z = fmaxf(-xy, 1.f + 1e-7f);
    float dist = acoshf(z);
    float d2 = 0.f;
    #pragma unroll
    for (int j = 0; j < 5; ++j){
      int c = lane + 64*j;
      nom[j] = yv[j] + xy*ms[j];
      float prd = nom[j]*nom[j];
      d2 += (c == 0) ? -prd : prd;
    }
    float den = sqrtf(fmaxf(wredf(d2), 1e-8f));
    float sc = dist / den;
    float u0 = __shfl(nom[0], 0, 64) * sc;
    float corr = -u0 / (1.f + m0);
    float nsum = 0.f;
    #pragma unroll
    for (int j = 0; j < 5; ++j){
      int c = lane + 64*j;
      float uc = nom[j]*sc + corr*(ms[j] + ((c == 0) ? 1.f : 0.f));
      nsum += uc*uc;
    }
    nsum = wredf(nsum);          // wave-uniform
    vsum += sqrtf(nsum);
  }
  if (lane == 0) part[wv] = vsum;
  __syncthreads();
  if (threadIdx.x == 0)
    atomicAdd(scal, part[0] + part[1] + part[2] + part[3]);
}

// ---------------- BN apply: rescale, transport to beta, expmap, relu, time --
__global__ void bn_apply_kernel(const float* __restrict__ y, const float* __restrict__ mean,
                                const float* __restrict__ beta, const float* __restrict__ gamma,
                                const float* __restrict__ scal, float* __restrict__ hout,
                                int P, int C){
  __shared__ float smean[260];
  __shared__ float sbeta[260];
  for (int i = threadIdx.x; i < C; i += blockDim.x){ smean[i] = mean[i]; sbeta[i] = beta[i]; }
  __syncthreads();
  int wv = threadIdx.x >> 6, lane = threadIdx.x & 63;
  int p = blockIdx.x*4 + wv;
  if (p >= P) return;
  const float* yp = y + (size_t)p * C;
  float yv[5], ms[5], bs[5], nom[5], uc[5], u2[5];
  #pragma unroll
  for (int j = 0; j < 5; ++j){
    int c = lane + 64*j;
    yv[j] = (c < C) ? yp[c] : 0.f;
    ms[j] = (c < C) ? smean[c] : 0.f;
    bs[j] = (c < C) ? sbeta[c] : 0.f;
  }
  float m0 = smean[0], b0 = sbeta[0];
  float d1 = 0.f;
  #pragma unroll
  for (int j = 0; j < 5; ++j){
    int c = lane + 64*j;
    float prd = yv[j]*ms[j];
    d1 += (c == 0) ? -prd : prd;
  }
  float xy = wredf(d1);
  float z = fmaxf(-xy, 1.f + 1e-7f);
  float dist = acoshf(z);
  float d2 = 0.f;
  #pragma unroll
  for (int j = 0; j < 5; ++j){
    nom[j] = yv[j] + xy*ms[j];
    int c = lane + 64*j;
    float prd = nom[j]*nom[j];
    d2 += (c == 0) ? -prd : prd;
  }
  float den = sqrtf(fmaxf(wredf(d2), 1e-8f));
  float sc = dist / den;
  float u0 = __shfl(nom[0], 0, 64) * sc;
  float corr = -u0 / (1.f + m0);
  float var = scal[0] / (float)P;
  float g = gamma[0] / (var + 1e-5f);
  #pragma unroll
  for (int j = 0; j < 5; ++j){
    int c = lane + 64*j;
    uc[j] = (nom[j]*sc + corr*(ms[j] + ((c == 0) ? 1.f : 0.f))) * g;
  }
  float d3 = 0.f;
  #pragma unroll
  for (int j = 0; j < 5; ++j){
    int c = lane + 64*j;
    float prd = uc[j]*bs[j];
    d3 += (c == 0) ? -prd : prd;
  }
  float cb = wredf(d3) / (1.f + b0);
  float d4 = 0.f;
  #pragma unroll
  for (int j = 0; j < 5; ++j){
    int c = lane + 64*j;
    u2[j] = uc[j] + cb*(bs[j] + ((c == 0) ? 1.f : 0.f));
    float prd = u2[j]*u2[j];
    d4 += (c == 0) ? -prd : prd;
  }
  float nu = sqrtf(fmaxf(wredf(d4), 1e-8f));
  float ch = coshf(nu), shn = sinhf(nu) / nu;
  float ssum = 0.f;
  float* hp = hout + (size_t)p * C;
  #pragma unroll
  for (int j = 0; j < 5; ++j){
    int c = lane + 64*j;
    if (c > 0 && c < C){
      float r = ch*sbeta[c] + shn*u2[j];
      r = fmaxf(r, 0.f);
      hp[c] = r;
      ssum += r*r;
    }
  }
  ssum = wredf(ssum);
  if (lane == 0) hp[0] = sqrtf(ssum + 1.f);
}

// ---------------- flatten h4 (B,256,257) -> (B,65537) + square sums ---------
__global__ void flatten_kernel(const float* __restrict__ h, float* __restrict__ flat,
                               float* __restrict__ scal){
  __shared__ float s[256];
  int tid = threadIdx.x;
  int idx = blockIdx.x*256 + tid;
  int b = idx >> 16, r = idx & 65535;
  int n = r >> 8, c = r & 255;
  float v = h[(((size_t)b << 8) + n)*257 + 1 + c];
  flat[(size_t)b*65537 + 1 + r] = v;
  s[tid] = v*v; __syncthreads();
  for (int st = 128; st; st >>= 1){ if (tid < st) s[tid] += s[tid+st]; __syncthreads(); }
  if (tid == 0) atomicAdd(&scal[1 + b], s[0]);
}

__global__ void flat_time_kernel(float* __restrict__ flat, const float* __restrict__ scal){
  int b = threadIdx.x;
  if (b < 32) flat[(size_t)b*65537] = sqrtf(scal[1 + b] + 1.f);
}

// ---------------- head GEMM: split-K, h in LDS, W streamed ------------------
__global__ __launch_bounds__(256) void fgemm_kernel(const float* __restrict__ flat,
    const float* __restrict__ wm, const float* __restrict__ wv,
    float* __restrict__ mvacc){
  __shared__ float hch[256*33];
  int tid = threadIdx.x;
  int k0 = blockIdx.x * 256;
  int obase = blockIdx.y * 32;
  {
    int k = k0 + tid;
    for (int b2 = 0; b2 < 32; ++b2){
      float v = (k < 65537) ? flat[(size_t)b2*65537 + k] : 0.f;
      hch[tid*33 + b2] = v;
    }
  }
  __syncthreads();
  int b = tid & 31, os = tid >> 5;
  const float* rows[4];
  float accv[4] = {0.f, 0.f, 0.f, 0.f};
  #pragma unroll
  for (int r = 0; r < 4; ++r){
    int o = obase + os + r*8;
    rows[r] = (o < 512) ? (wm + (size_t)(o + 1)*65537) : (wv + (size_t)(o - 511)*65537);
  }
  int kRem = min(256, 65537 - k0);
  int k4 = kRem & ~3;
  for (int k = 0; k < k4; k += 4){
    float h0 = hch[(k+0)*33 + b], h1 = hch[(k+1)*33 + b];
    float h2 = hch[(k+2)*33 + b], h3 = hch[(k+3)*33 + b];
    #pragma unroll
    for (int r = 0; r < 4; ++r){
      const float* rw = rows[r] + k0 + k;
      accv[r] += h0*rw[0] + h1*rw[1] + h2*rw[2] + h3*rw[3];
    }
  }
  for (int k = k4; k < kRem; ++k){
    float hv = hch[k*33 + b];
    #pragma unroll
    for (int r = 0; r < 4; ++r) accv[r] += hv * rows[r][k0 + k];
  }
  #pragma unroll
  for (int r = 0; r < 4; ++r){
    int o = obase + os + r*8;
    atomicAdd(&mvacc[o*32 + b], accv[r]);
  }
}

// ---------------- finalize: bias, time, softplus ----------------------------
__global__ void finalize_kernel(const float* __restrict__ mvacc, const float* __restrict__ bm,
                                const float* __restrict__ bv, float* __restrict__ out){
  __shared__ float s[256];
  int b = blockIdx.x, tid = threadIdx.x;
  float m0 = mvacc[tid*32 + b] + bm[tid + 1];
  float m1 = mvacc[(tid + 256)*32 + b] + bm[tid + 257];
  s[tid] = m0*m0 + m1*m1; __syncthreads();
  for (int st = 128; st; st >>= 1){ if (tid < st) s[tid] += s[tid+st]; __syncthreads(); }
  float t = sqrtf(s[0] + 1.f);
  float* om = out + (size_t)b*513;
  om[1 + tid] = m0;
  om[1 + tid + 256] = m1;
  if (tid == 0) om[0] = t;
  float v0 = mvacc[(512 + tid)*32 + b] + bv[tid + 1];
  float v1 = mvacc[(512 + tid + 256)*32 + b] + bv[tid + 257];
  float sp0 = fmaxf(v0, 0.f) + log1pf(expf(-fabsf(v0)));
  float sp1 = fmaxf(v1, 0.f) + log1pf(expf(-fabsf(v1)));
  float* ov = out + 32*513 + (size_t)b*512;
  ov[tid] = fmaxf(sp0, 1e-5f);
  ov[tid + 256] = fmaxf(sp1, 1e-5f);
}

extern "C" void kernel_launch(void* const* d_in, const int* in_sizes, int n_in,
                              void* d_out, int out_size, void* d_ws, size_t ws_size,
                              hipStream_t stream){
  const float* x  = (const float*)d_in[0];
  const float* cw[4] = {(const float*)d_in[1], (const float*)d_in[5], (const float*)d_in[9],  (const float*)d_in[13]};
  const float* cb[4] = {(const float*)d_in[2], (const float*)d_in[6], (const float*)d_in[10], (const float*)d_in[14]};
  const float* bb[4] = {(const float*)d_in[3], (const float*)d_in[7], (const float*)d_in[11], (const float*)d_in[15]};
  const float* bg[4] = {(const float*)d_in[4], (const float*)d_in[8], (const float*)d_in[12], (const float*)d_in[16]};
  const float* wm = (const float*)d_in[17];
  const float* bm = (const float*)d_in[18];
  const float* wv = (const float*)d_in[19];
  const float* bv = (const float*)d_in[20];
  float* ws = (float*)d_ws;

  // workspace layout (floats)
  float* S[3] = { ws, ws + 9000000, ws + 26400000 };      // 9M / 17.4M / 17.4M
  float* red1  = ws + 43800000;                           // up to 32*257
  float* meanp = ws + 43810000;                           // up to 257
  float* scal  = ws + 43811000;                           // [0]=var sum, [1..32]=flat sq
  float* mvacc = ws + 43812000;                           // 1024*32

  hipMemsetAsync(mvacc, 0, 32768*sizeof(float), stream);

  h0_kernel<<<8192, 256, 0, stream>>>(x, S[0]);

  const int HinA[4]  = {256, 128, 64, 32};
  const int SinA[4]  = {3, 32, 64, 128};
  const int HoA[4]   = {128, 64, 32, 16};
  const int CoutA[4] = {33, 65, 129, 257};
  const int KA[4]    = {28, 289, 577, 1153};

  int cur = 0;
  for (int i = 0; i < 4; ++i){
    int Hin = HinA[i], Win = HinA[i], Cin = SinA[i] + 1;
    int Ho = HoA[i], Wo = HoA[i], Cout = CoutA[i], K = KA[i];
    float* hin  = S[cur];
    float* y    = S[(cur + 1) % 3];
    float* hout = S[(cur + 2) % 3];
    int tiles = (Ho/8) * (Wo/8);
    dim3 g(tiles, 32, (Cout - 1 + 63)/64);
    conv_kernel<<<g, 256, 0, stream>>>(hin, cw[i], cb[i], y, Hin, Win, Cin, Ho, Wo, Cout, K);
    int N = Ho * Wo;
    int P = 32 * N;
    time_kernel<<<(P + 3)/4, 256, 0, stream>>>(y, P, Cout);
    hipMemsetAsync(red1, 0, 32*Cout*sizeof(float), stream);
    int SPLIT = (N >= 16384) ? 64 : ((N >= 4096) ? 16 : ((N >= 1024) ? 4 : 1));
    rsum_kernel<<<dim3(SPLIT, 32), 256, 0, stream>>>(y, red1, N, Cout, SPLIT);
    bn_stats_kernel<<<1, 256, 0, stream>>>(red1, meanp, scal, 32, N, Cout);
    int vblocks = min((P + 3)/4, 2048);
    bn_var_kernel<<<vblocks, 256, 0, stream>>>(y, meanp, scal, P, Cout);
    bn_apply_kernel<<<(P + 3)/4, 256, 0, stream>>>(y, meanp, bb[i], bg[i], scal, hout, P, Cout);
    cur = (cur + 2) % 3;
  }

  // h4 now in S[cur] (== S[2]); flatten into S[0]
  float* flatp = S[0];
  flatten_kernel<<<8192, 256, 0, stream>>>(S[cur], flatp, scal);
  flat_time_kernel<<<1, 64, 0, stream>>>(flatp, scal);
  fgemm_kernel<<<dim3(257, 32), 256, 0, stream>>>(flatp, wm, wv, mvacc);
  finalize_kernel<<<32, 256, 0, stream>>>(mvacc, bm, bv, (float*)d_out);
}